// Round 1
// baseline (254.932 us; speedup 1.0000x reference)
//
#include <hip/hip_runtime.h>
#include <math.h>

#define NQ 196
#define BATCH 4
#define HD 512            // H * D_K == D_MODEL
#define MROWS (BATCH*NQ)  // 784

struct Ptrs {
  const float* X[3];
  const float* W[3];
  const float* Bb[3];
  float* C[3];
};

// C = X @ W^T + bias, optional gating epilogue: c = sigmoid(gate*c)*c
// X: (M,K) row-major, W: (N,K) row-major, C: (M,N). N,K multiples of 64/16.
__global__ __launch_bounds__(256)
void gemm3_kernel(Ptrs p, const float* __restrict__ gate, int M, int K, int N) {
  const int z = blockIdx.z;
  const float* __restrict__ X  = p.X[z];
  const float* __restrict__ W  = p.W[z];
  const float* __restrict__ Bb = p.Bb[z];
  float* __restrict__ C        = p.C[z];

  __shared__ float As[16][68];  // [k][m], padded to 68 for bank spread + 16B align
  __shared__ float Bs[16][68];  // [k][n]

  const int t  = threadIdx.x;
  const int m0 = blockIdx.x * 64;
  const int n0 = blockIdx.y * 64;

  const int lr = t >> 2;          // 0..63 : tile row loaded by this thread
  const int lc = (t & 3) << 2;    // 0,4,8,12 : k offset (float4)
  const int tm = (t & 15) << 2;   // 4 m's computed
  const int tn = (t >> 4) << 2;   // 4 n's computed

  float acc[4][4] = {};

  for (int k0 = 0; k0 < K; k0 += 16) {
    float4 xa = make_float4(0.f, 0.f, 0.f, 0.f);
    if (m0 + lr < M)
      xa = *(const float4*)(X + (size_t)(m0 + lr) * K + k0 + lc);
    float4 wb = *(const float4*)(W + (size_t)(n0 + lr) * K + k0 + lc);

    __syncthreads();  // previous tile fully consumed
    As[lc + 0][lr] = xa.x; As[lc + 1][lr] = xa.y;
    As[lc + 2][lr] = xa.z; As[lc + 3][lr] = xa.w;
    Bs[lc + 0][lr] = wb.x; Bs[lc + 1][lr] = wb.y;
    Bs[lc + 2][lr] = wb.z; Bs[lc + 3][lr] = wb.w;
    __syncthreads();

    #pragma unroll
    for (int kk = 0; kk < 16; ++kk) {
      float4 a = *(const float4*)&As[kk][tm];
      float4 b = *(const float4*)&Bs[kk][tn];
      float av[4] = {a.x, a.y, a.z, a.w};
      float bv[4] = {b.x, b.y, b.z, b.w};
      #pragma unroll
      for (int i = 0; i < 4; ++i)
        #pragma unroll
        for (int j = 0; j < 4; ++j)
          acc[i][j] += av[i] * bv[j];
    }
  }

  #pragma unroll
  for (int i = 0; i < 4; ++i) {
    int m = m0 + tm + i;
    if (m >= M) break;
    #pragma unroll
    for (int j = 0; j < 4; ++j) {
      int n = n0 + tn + j;
      float c = acc[i][j] + Bb[n];
      if (gate) {
        float qg = gate[(size_t)m * N + n];
        c = __fdividef(c, 1.f + __expf(-qg * c));  // sigmoid(qg*c)*c
      }
      C[(size_t)m * N + n] = c;
    }
  }
}

// One block per (q, b). 512 threads: wave = head h, lane = d.
// Online-softmax single pass over k; fused sigmoid(q*k)*v gating.
__global__ __launch_bounds__(512)
void attn_kernel(const float* __restrict__ qsg, const float* __restrict__ kpg,
                 const float* __restrict__ vpg, const float* __restrict__ scg,
                 float* __restrict__ img) {
  const int b  = blockIdx.y;
  const int q  = blockIdx.x;
  const int hd = threadIdx.x;
  const int h  = hd >> 6;

  const size_t rowq = (size_t)(b * NQ + q) * HD;
  const float qs = qsg[rowq + hd];
  const float* __restrict__ sc = scg + ((size_t)h * NQ + q) * NQ;  // scale[0,h,q,:]
  const float* __restrict__ kp = kpg + (size_t)b * NQ * HD + hd;
  const float* __restrict__ vp = vpg + (size_t)b * NQ * HD + hd;

  float m = -1e30f, l = 0.f, acc = 0.f;

  for (int k = 0; k < NQ; ++k) {
    float kv = kp[(size_t)k * HD];
    float vv = vp[(size_t)k * HD];
    float t = qs * kv;
    // 64-lane butterfly sum -> per-head QK dot, identical in all lanes
    float s = t;
    #pragma unroll
    for (int off = 32; off > 0; off >>= 1) s += __shfl_xor(s, off, 64);
    float a = s * sc[k];
    float g = __fdividef(vv, 1.f + __expf(-t));  // sigmoid(q*k)*v
    if (a > m) {            // wave-uniform branch (a,m uniform in wave)
      float alpha = __expf(m - a);
      l   = l * alpha + 1.f;
      acc = acc * alpha + g;
      m = a;
    } else {
      float pe = __expf(a - m);
      l   += pe;
      acc += pe * g;
    }
  }
  img[rowq + hd] = __fdividef(acc, l);
}

extern "C" void kernel_launch(void* const* d_in, const int* in_sizes, int n_in,
                              void* d_out, int out_size, void* d_ws, size_t ws_size,
                              hipStream_t stream) {
  const float* queries = (const float*)d_in[0];
  const float* keys    = (const float*)d_in[1];
  const float* values  = (const float*)d_in[2];
  const float* Wq = (const float*)d_in[3];
  const float* bq = (const float*)d_in[4];
  const float* Wk = (const float*)d_in[5];
  const float* bk = (const float*)d_in[6];
  const float* Wv = (const float*)d_in[7];
  const float* bv = (const float*)d_in[8];
  const float* Wo = (const float*)d_in[9];
  const float* bo = (const float*)d_in[10];
  const float* scale = (const float*)d_in[11];

  float* ws = (float*)d_ws;
  const size_t NEL = (size_t)MROWS * HD;  // 784*512
  float* q_sig = ws;
  float* k_p   = ws + NEL;
  float* v_p   = ws + 2 * NEL;
  float* image = ws + 3 * NEL;

  // 1) projections: q_sig, k_p, v_p
  Ptrs pp;
  pp.X[0] = queries; pp.X[1] = keys; pp.X[2] = values;
  pp.W[0] = Wq;      pp.W[1] = Wk;   pp.W[2] = Wv;
  pp.Bb[0] = bq;     pp.Bb[1] = bk;  pp.Bb[2] = bv;
  pp.C[0] = q_sig;   pp.C[1] = k_p;  pp.C[2] = v_p;
  dim3 g1((MROWS + 63) / 64, HD / 64, 3);
  gemm3_kernel<<<g1, 256, 0, stream>>>(pp, nullptr, MROWS, HD, HD);

  // 2) fused att + softmax + gated PV -> image
  dim3 g2(NQ, BATCH, 1);
  attn_kernel<<<g2, 512, 0, stream>>>(q_sig, k_p, v_p, scale, image);

  // 3) out = image @ Wo^T + bo, then sigmoid(q_sig*out)*out
  Ptrs po;
  po.X[0] = image; po.X[1] = nullptr; po.X[2] = nullptr;
  po.W[0] = Wo;    po.W[1] = nullptr; po.W[2] = nullptr;
  po.Bb[0] = bo;   po.Bb[1] = nullptr; po.Bb[2] = nullptr;
  po.C[0] = (float*)d_out; po.C[1] = nullptr; po.C[2] = nullptr;
  dim3 g3((MROWS + 63) / 64, HD / 64, 1);
  gemm3_kernel<<<g3, 256, 0, stream>>>(po, q_sig, MROWS, HD, HD);
}

// Round 2
// 227.237 us; speedup vs baseline: 1.1219x; 1.1219x over previous
//
#include <hip/hip_runtime.h>
#include <math.h>

#define NQ 196
#define BATCH 4
#define HD 512            // H * D_K == D_MODEL
#define NH 8
#define DK 64
#define MROWS (BATCH*NQ)  // 784

struct Ptrs {
  const float* X[3];
  const float* W[3];
  const float* Bb[3];
  float* C[3];
};

// C = X @ W^T + bias, optional gating epilogue: c = sigmoid(gate*c)*c
// 512 threads: two K-split groups of 256; 64x64 tile, 4x4 microtile;
// double-buffered LDS, one barrier per k-tile.
__global__ __launch_bounds__(512)
void gemm3_kernel(Ptrs p, const float* __restrict__ gate, int M, int K, int N) {
  const int z = blockIdx.z;
  const float* __restrict__ X  = p.X[z];
  const float* __restrict__ W  = p.W[z];
  const float* __restrict__ Bb = p.Bb[z];
  float* __restrict__ C        = p.C[z];

  // A region: [group][buf][16][68], then B region same. 8704 floats = 34.8 KB
  __shared__ float smem[2 * 2 * 16 * 68 * 2];
  float* const Abase = smem;
  float* const Bbase = smem + 4 * 16 * 68;

  const int t  = threadIdx.x;
  const int g  = t >> 8;        // k-split group 0/1
  const int tt = t & 255;
  const int m0 = blockIdx.x * 64;
  const int n0 = blockIdx.y * 64;

  const int lr = tt >> 2;          // 0..63 tile row loaded
  const int lc = (tt & 3) << 2;    // 0,4,8,12 k offset (float4)
  const int tm = (tt & 15) << 2;   // 4 m's computed
  const int tn = (tt >> 4) << 2;   // 4 n's computed

  const int kb = g * (K >> 1);
  const int T  = (K >> 1) >> 4;    // k-tiles per group

  const bool mok = (m0 + lr) < M;
  const float* Xr = X + (size_t)(m0 + lr) * K + kb + lc;
  const float* Wr = W + (size_t)(n0 + lr) * K + kb + lc;

  float acc[4][4] = {};

  // prologue: stage tile 0
  {
    float4 xa = make_float4(0.f, 0.f, 0.f, 0.f);
    if (mok) xa = *(const float4*)Xr;
    float4 wb = *(const float4*)Wr;
    float* A0 = Abase + (g * 2 + 0) * 16 * 68;
    float* B0 = Bbase + (g * 2 + 0) * 16 * 68;
    A0[(lc + 0) * 68 + lr] = xa.x; A0[(lc + 1) * 68 + lr] = xa.y;
    A0[(lc + 2) * 68 + lr] = xa.z; A0[(lc + 3) * 68 + lr] = xa.w;
    B0[(lc + 0) * 68 + lr] = wb.x; B0[(lc + 1) * 68 + lr] = wb.y;
    B0[(lc + 2) * 68 + lr] = wb.z; B0[(lc + 3) * 68 + lr] = wb.w;
  }
  __syncthreads();

  for (int it = 0; it < T; ++it) {
    const int buf = it & 1;
    // prefetch next tile into registers (overlaps with FMA below)
    float4 nxa = make_float4(0.f, 0.f, 0.f, 0.f);
    float4 nwb = make_float4(0.f, 0.f, 0.f, 0.f);
    if (it + 1 < T) {
      if (mok) nxa = *(const float4*)(Xr + (it + 1) * 16);
      nwb = *(const float4*)(Wr + (it + 1) * 16);
    }

    const float* A = Abase + (g * 2 + buf) * 16 * 68;
    const float* B = Bbase + (g * 2 + buf) * 16 * 68;
    #pragma unroll
    for (int kk = 0; kk < 16; ++kk) {
      float4 a = *(const float4*)&A[kk * 68 + tm];
      float4 b = *(const float4*)&B[kk * 68 + tn];
      float av[4] = {a.x, a.y, a.z, a.w};
      float bv[4] = {b.x, b.y, b.z, b.w};
      #pragma unroll
      for (int i = 0; i < 4; ++i)
        #pragma unroll
        for (int j = 0; j < 4; ++j)
          acc[i][j] += av[i] * bv[j];
    }

    if (it + 1 < T) {
      const int nb = buf ^ 1;
      float* An = Abase + (g * 2 + nb) * 16 * 68;
      float* Bn = Bbase + (g * 2 + nb) * 16 * 68;
      An[(lc + 0) * 68 + lr] = nxa.x; An[(lc + 1) * 68 + lr] = nxa.y;
      An[(lc + 2) * 68 + lr] = nxa.z; An[(lc + 3) * 68 + lr] = nxa.w;
      Bn[(lc + 0) * 68 + lr] = nwb.x; Bn[(lc + 1) * 68 + lr] = nwb.y;
      Bn[(lc + 2) * 68 + lr] = nwb.z; Bn[(lc + 3) * 68 + lr] = nwb.w;
      __syncthreads();
    }
  }
  __syncthreads();  // all LDS tile traffic done; safe to alias cbuf

  float* cbuf = smem;  // 4096 floats, aliases A-buffers
  if (g == 1) {
    #pragma unroll
    for (int i = 0; i < 4; ++i)
      #pragma unroll
      for (int j = 0; j < 4; ++j)
        cbuf[(tm + i) * 64 + tn + j] = acc[i][j];
  }
  __syncthreads();
  if (g == 0) {
    #pragma unroll
    for (int i = 0; i < 4; ++i) {
      const int m = m0 + tm + i;
      if (m < M) {
        #pragma unroll
        for (int j = 0; j < 4; ++j) {
          const int n = n0 + tn + j;
          float c = acc[i][j] + cbuf[(tm + i) * 64 + tn + j] + Bb[n];
          if (gate) {
            float qg = gate[(size_t)m * N + n];
            c = __fdividef(c, 1.f + __expf(-qg * c));  // sigmoid(qg*c)*c
          }
          C[(size_t)m * N + n] = c;
        }
      }
    }
  }
}

// scores + softmax: p[b,h,q,k] = softmax_k( scale[h,q,k] * sum_d qs*kp )
// block = (qchunk of 14, h, b), 256 threads; K head-slice staged in LDS.
__global__ __launch_bounds__(256)
void scores_kernel(const float* __restrict__ qsg, const float* __restrict__ kpg,
                   const float* __restrict__ scg, float* __restrict__ pbuf) {
  const int b  = blockIdx.z;
  const int h  = blockIdx.y;
  const int q0 = blockIdx.x * 14;
  const int t  = threadIdx.x;

  __shared__ float klds[NQ * 65];   // padded stride 65: conflict-free col reads
  __shared__ float qlds[14 * 64];
  __shared__ float red[8];

  const float* kp = kpg + (size_t)b * NQ * HD + h * DK;
  for (int idx = t; idx < NQ * 16; idx += 256) {
    int r = idx >> 4, j = (idx & 15) << 2;
    float4 v = *(const float4*)(kp + (size_t)r * HD + j);
    float* d = &klds[r * 65 + j];
    d[0] = v.x; d[1] = v.y; d[2] = v.z; d[3] = v.w;
  }
  const float* qp = qsg + ((size_t)b * NQ + q0) * HD + h * DK;
  for (int idx = t; idx < 14 * 16; idx += 256) {
    int r = idx >> 4, j = (idx & 15) << 2;
    float4 v = *(const float4*)(qp + (size_t)r * HD + j);
    float* d = &qlds[r * 64 + j];
    d[0] = v.x; d[1] = v.y; d[2] = v.z; d[3] = v.w;
  }
  __syncthreads();

  for (int qi = 0; qi < 14; ++qi) {
    const int q = q0 + qi;
    float att = -1e30f;
    if (t < NQ) {
      const float* kr = &klds[t * 65];
      const float* qr = &qlds[qi * 64];
      float dot = 0.f;
      #pragma unroll 16
      for (int d = 0; d < DK; ++d) dot += qr[d] * kr[d];
      att = dot * scg[((size_t)h * NQ + q) * NQ + t];
    }
    // block max
    float m = att;
    #pragma unroll
    for (int off = 32; off; off >>= 1) m = fmaxf(m, __shfl_xor(m, off, 64));
    if ((t & 63) == 0) red[t >> 6] = m;
    __syncthreads();
    m = fmaxf(fmaxf(red[0], red[1]), fmaxf(red[2], red[3]));
    const float e = (t < NQ) ? __expf(att - m) : 0.f;
    float s = e;
    #pragma unroll
    for (int off = 32; off; off >>= 1) s += __shfl_xor(s, off, 64);
    __syncthreads();
    if ((t & 63) == 0) red[t >> 6] = s;
    __syncthreads();
    s = red[0] + red[1] + red[2] + red[3];
    const float rinv = __fdividef(1.f, s);
    if (t < NQ)
      pbuf[(((size_t)(b * NH + h) * NQ) + q) * NQ + t] = e * rinv;
    __syncthreads();
  }
}

// image[b,q,hd] = sum_k p[b,h,q,k] * sigmoid(qs*kv) * vv  — no cross-lane ops
__global__ __launch_bounds__(512)
void pv_kernel(const float* __restrict__ qsg, const float* __restrict__ kpg,
               const float* __restrict__ vpg, const float* __restrict__ pbuf,
               float* __restrict__ img) {
  const int b  = blockIdx.y;
  const int q  = blockIdx.x;
  const int hd = threadIdx.x;
  const int h  = hd >> 6;

  const size_t rowq = (size_t)(b * NQ + q) * HD;
  const float qs = qsg[rowq + hd];
  const float* kp = kpg + (size_t)b * NQ * HD + hd;
  const float* vp = vpg + (size_t)b * NQ * HD + hd;
  const float* pr = pbuf + (((size_t)(b * NH + h) * NQ) + q) * NQ;

  float acc = 0.f;
  #pragma unroll 4
  for (int k = 0; k < NQ; ++k) {
    float kv = kp[(size_t)k * HD];
    float vv = vp[(size_t)k * HD];
    float tq = qs * kv;
    float g  = __fdividef(vv, 1.f + __expf(-tq));  // sigmoid(qs*kv)*vv
    acc += pr[k] * g;
  }
  img[rowq + hd] = acc;
}

extern "C" void kernel_launch(void* const* d_in, const int* in_sizes, int n_in,
                              void* d_out, int out_size, void* d_ws, size_t ws_size,
                              hipStream_t stream) {
  const float* queries = (const float*)d_in[0];
  const float* keys    = (const float*)d_in[1];
  const float* values  = (const float*)d_in[2];
  const float* Wq = (const float*)d_in[3];
  const float* bq = (const float*)d_in[4];
  const float* Wk = (const float*)d_in[5];
  const float* bk = (const float*)d_in[6];
  const float* Wv = (const float*)d_in[7];
  const float* bv = (const float*)d_in[8];
  const float* Wo = (const float*)d_in[9];
  const float* bo = (const float*)d_in[10];
  const float* scale = (const float*)d_in[11];

  float* ws = (float*)d_ws;
  const size_t NEL = (size_t)MROWS * HD;  // 784*512
  float* q_sig = ws;
  float* k_p   = ws + NEL;
  float* v_p   = ws + 2 * NEL;
  float* image = ws + 3 * NEL;
  float* pbuf  = ws + 4 * NEL;            // 4*8*196*196 floats ~ 4.9 MB

  // 1) projections
  Ptrs pp;
  pp.X[0] = queries; pp.X[1] = keys; pp.X[2] = values;
  pp.W[0] = Wq;      pp.W[1] = Wk;   pp.W[2] = Wv;
  pp.Bb[0] = bq;     pp.Bb[1] = bk;  pp.Bb[2] = bv;
  pp.C[0] = q_sig;   pp.C[1] = k_p;  pp.C[2] = v_p;
  dim3 g1((MROWS + 63) / 64, HD / 64, 3);
  gemm3_kernel<<<g1, 512, 0, stream>>>(pp, nullptr, MROWS, HD, HD);

  // 2a) scores + softmax -> pbuf
  dim3 g2(NQ / 14, NH, BATCH);
  scores_kernel<<<g2, 256, 0, stream>>>(q_sig, k_p, scale, pbuf);

  // 2b) gated PV -> image
  dim3 g3(NQ, BATCH, 1);
  pv_kernel<<<g3, 512, 0, stream>>>(q_sig, k_p, v_p, pbuf, image);

  // 3) out = image @ Wo^T + bo, then sigmoid(q_sig*out)*out
  Ptrs po;
  po.X[0] = image; po.X[1] = image; po.X[2] = image;
  po.W[0] = Wo;    po.W[1] = Wo;    po.W[2] = Wo;
  po.Bb[0] = bo;   po.Bb[1] = bo;   po.Bb[2] = bo;
  po.C[0] = (float*)d_out; po.C[1] = (float*)d_out; po.C[2] = (float*)d_out;
  dim3 g4((MROWS + 63) / 64, HD / 64, 1);
  gemm3_kernel<<<g4, 512, 0, stream>>>(po, q_sig, MROWS, HD, HD);
}